// Round 5
// baseline (73.765 us; speedup 1.0000x reference)
//
#include <hip/hip_runtime.h>
#include <cstddef>

// Problem constants (fixed by reference setup_inputs):
//   out_seg: (8,6,11,192,192,1) f32  -> logits (N=48, K=11, P=36864) contiguous
//   segmentations: (8,6,192,192) int -> tgt (N, P)  (int32 on device, verified r2)
//   label: (8,6) int                 -> mask (N)
constexpr int BLOCK  = 256;
constexpr int KCLS   = 11;
constexpr int PPIX   = 192 * 192;            // 36864
constexpr int NROW   = 48;                   // B*S
constexpr int PVEC   = PPIX / 4;             // 9216 float4/int4 groups per plane
constexpr int CHUNKS = PVEC / BLOCK;         // 36 chunks per row (exact)
constexpr int NBLK   = CHUNKS * NROW;        // 1728 blocks

__device__ __forceinline__ float waveReduceSum(float v) {
#pragma unroll
    for (int off = 32; off > 0; off >>= 1)
        v += __shfl_down(v, off, 64);
    return v;
}

// Fused: focal partial sums + last-block final reduction.
//  - predicated plane loads: only fetch plane k's float4 if one of this
//    thread's 4 pixels targets class k (exec-masked -> touched-line-minimum
//    HBM traffic, ~34 MB, while staying coalesced within each plane)
//  - row-interleaved block mapping for even load balance
//  - threadfence+atomic-counter last-block reduction (deterministic: fixed
//    reduction order independent of which block runs last)
__global__ __launch_bounds__(BLOCK)
void focal_fused(const float4* __restrict__ logits4,
                 const int4*   __restrict__ seg4,
                 const int*    __restrict__ label,
                 float*        __restrict__ partial,
                 unsigned*     __restrict__ counter,
                 float*        __restrict__ out) {
    const int b = blockIdx.x;
    const int n = b % NROW;                  // interleave rows across blocks
    const int x = b / NROW;                  // pixel chunk within row
    __shared__ float smem[BLOCK / 64];
    __shared__ float fsum[BLOCK / 64];
    __shared__ float fcnt[BLOCK / 64];
    __shared__ bool  isLast;

    float acc = 0.0f;
    if (label[n] != 0) {                     // block-uniform: whole row masked
        const int g = x * BLOCK + (int)threadIdx.x;
        const int4 s = seg4[(size_t)n * PVEC + g];    // 4 class idx, coalesced
        const size_t base = (size_t)n * KCLS * PVEC + g;

        float4 v[KCLS];
#pragma unroll
        for (int k = 0; k < KCLS; ++k) {
            // per-lane predicate: masked-off lanes generate no HBM traffic
            if (s.x == k || s.y == k || s.z == k || s.w == k)
                v[k] = logits4[base + (size_t)k * PVEC];
        }

        const int t[4] = { s.x, s.y, s.z, s.w };
#pragma unroll
        for (int j = 0; j < 4; ++j) {
            float lp = (&v[0].x)[j];         // valid iff t[j]==0 (then loaded)
#pragma unroll
            for (int k = 1; k < KCLS; ++k)
                lp = (t[j] == k) ? (&v[k].x)[j] : lp;   // cndmask chain
            const float pt = expf(lp);
            const float u  = 1.0f - pt;
            const float u2 = u * u;
            const float u6 = u2 * u2 * u2;   // (1-pt)^6, exact even power
            acc = fmaf(-u6, lp, acc);        // -(1-pt)^6 * logpt
        }
    }

    // deterministic block reduction -> partial[b] (always written)
    acc = waveReduceSum(acc);
    const int lane = threadIdx.x & 63;
    const int wid  = threadIdx.x >> 6;
    if (lane == 0) smem[wid] = acc;
    __syncthreads();
    if (threadIdx.x == 0) {
        float s = smem[0];
#pragma unroll
        for (int w = 1; w < BLOCK / 64; ++w) s += smem[w];
        partial[b] = s;
        __threadfence();                     // release: publish partial[b]
        const unsigned old = atomicAdd(counter, 1u);   // device scope (G12)
        isLast = (old == NBLK - 1);
    }
    __syncthreads();

    if (isLast) {                            // exactly one block runs this
        __threadfence();                     // acquire: see all partials
        float s = 0.0f;
        for (int i = threadIdx.x; i < NBLK; i += BLOCK) s += partial[i];
        float c = (threadIdx.x < NROW && label[threadIdx.x] != 0) ? 1.0f : 0.0f;
        s = waveReduceSum(s);
        c = waveReduceSum(c);
        if (lane == 0) { fsum[wid] = s; fcnt[wid] = c; }
        __syncthreads();
        if (threadIdx.x == 0) {
            const float total = fsum[0] + fsum[1] + fsum[2] + fsum[3];
            const float cnt   = fcnt[0] + fcnt[1] + fcnt[2] + fcnt[3];
            const float loss  = total / cnt;
            out[0] = loss;   // loss (shape (1,))
            out[1] = 0.0f;   // recon = jnp.asarray(0)
            out[2] = loss;   // loss again (3rd tuple element)
        }
    }
}

extern "C" void kernel_launch(void* const* d_in, const int* in_sizes, int n_in,
                              void* d_out, int out_size, void* d_ws, size_t ws_size,
                              hipStream_t stream) {
    const float4* logits4 = (const float4*)d_in[0];  // out_seg
    const int4*   seg4    = (const int4*)d_in[1];    // segmentations
    const int*    label   = (const int*)d_in[2];     // label
    float*    out     = (float*)d_out;
    float*    partial = (float*)d_ws;                        // NBLK floats
    unsigned* counter = (unsigned*)(partial + NBLK);         // 1 uint after

    // ws is poisoned 0xAA once and never re-poisoned: zero the counter each
    // call (async memset is graph-capture-safe; harness uses it itself)
    hipMemsetAsync(counter, 0, sizeof(unsigned), stream);
    focal_fused<<<NBLK, BLOCK, 0, stream>>>(logits4, seg4, label,
                                            partial, counter, out);
}

// Round 6
// 18.191 us; speedup vs baseline: 4.0550x; 4.0550x over previous
//
#include <hip/hip_runtime.h>
#include <cstddef>

// Problem constants (fixed by reference setup_inputs):
//   out_seg: (8,6,11,192,192,1) f32  -> logits (N=48, K=11, P=36864) contiguous
//   segmentations: (8,6,192,192) int -> tgt (N, P)  (int32 on device)
//   label: (8,6) int                 -> mask (N)
constexpr int BLOCK = 256;
constexpr int KCLS  = 11;
constexpr int PPIX  = 192 * 192;              // 36864
constexpr int NROW  = 48;                     // B*S
constexpr int PVEC  = PPIX / 4;               // 9216 float4/int4 groups per plane
constexpr int GRIDX = PVEC / BLOCK;           // 36 blocks per row (exact)

__device__ __forceinline__ float waveReduceSum(float v) {
#pragma unroll
    for (int off = 32; off > 0; off >>= 1)
        v += __shfl_down(v, off, 64);
    return v;
}

// Stream all 11 class planes with coalesced float4 loads into NAMED registers
// (no array -> no scratch, round-4's failure mode), select target class per
// pixel with a nested-ternary cndmask chain. All 12 loads unconditional and
// independent -> fully pipelined global_load_dwordx4.
__global__ __launch_bounds__(BLOCK)
void focal_partial(const float4* __restrict__ logits4,
                   const int4*   __restrict__ seg4,
                   const int*    __restrict__ label,
                   float*        __restrict__ partial) {
    const int n   = blockIdx.y;
    const int bid = blockIdx.y * gridDim.x + blockIdx.x;
    __shared__ float smem[BLOCK / 64];

    float acc = 0.0f;
    if (label[n] != 0) {                      // block-uniform: whole row masked
        const int g = blockIdx.x * BLOCK + (int)threadIdx.x;
        const int4 s = seg4[(size_t)n * PVEC + g];     // 4 class idx, coalesced
        const size_t base = (size_t)n * KCLS * PVEC + g;

#define LDP(k) logits4[base + (size_t)(k) * PVEC]
        const float4 v0 = LDP(0),  v1 = LDP(1),  v2 = LDP(2),  v3 = LDP(3);
        const float4 v4 = LDP(4),  v5 = LDP(5),  v6 = LDP(6),  v7 = LDP(7);
        const float4 v8 = LDP(8),  v9 = LDP(9),  v10 = LDP(10);
#undef LDP

        // nested-ternary select: compiles to v_cmp + v_cndmask chain, all in
        // VGPRs (compile-time component access, no address-taking)
#define SELC(t, c) ((t) == 10 ? v10.c : (t) == 9 ? v9.c : (t) == 8 ? v8.c : \
                    (t) == 7  ? v7.c  : (t) == 6 ? v6.c : (t) == 5 ? v5.c : \
                    (t) == 4  ? v4.c  : (t) == 3 ? v3.c : (t) == 2 ? v2.c : \
                    (t) == 1  ? v1.c  : v0.c)
        const float lp0 = SELC(s.x, x);
        const float lp1 = SELC(s.y, y);
        const float lp2 = SELC(s.z, z);
        const float lp3 = SELC(s.w, w);
#undef SELC

#define FOCAL(lp) do {                        \
        const float pt = expf(lp);            \
        const float u  = 1.0f - pt;           \
        const float u2 = u * u;               \
        const float u6 = u2 * u2 * u2;        \
        acc = fmaf(-u6, (lp), acc);           \
    } while (0)
        FOCAL(lp0); FOCAL(lp1); FOCAL(lp2); FOCAL(lp3);
#undef FOCAL
    }

    // deterministic block reduction
    acc = waveReduceSum(acc);
    const int lane = threadIdx.x & 63;
    const int wid  = threadIdx.x >> 6;
    if (lane == 0) smem[wid] = acc;
    __syncthreads();
    if (threadIdx.x == 0) {
        float sum = smem[0];
#pragma unroll
        for (int w = 1; w < BLOCK / 64; ++w) sum += smem[w];
        partial[bid] = sum;                   // always written (ws poisoned 0xAA)
    }
}

__global__ __launch_bounds__(256)
void focal_final(const float* __restrict__ partial, int nPartial,
                 const int*   __restrict__ label,   int nLabel,
                 float*       __restrict__ out) {
    __shared__ float ssum[4];
    __shared__ float scnt[4];

    float s = 0.0f;
    for (int i = threadIdx.x; i < nPartial; i += 256) s += partial[i];
    float c = 0.0f;
    for (int i = threadIdx.x; i < nLabel; i += 256) c += (label[i] != 0) ? 1.0f : 0.0f;

    s = waveReduceSum(s);
    c = waveReduceSum(c);
    const int lane = threadIdx.x & 63;
    const int wid  = threadIdx.x >> 6;
    if (lane == 0) { ssum[wid] = s; scnt[wid] = c; }
    __syncthreads();
    if (threadIdx.x == 0) {
        const float total = ssum[0] + ssum[1] + ssum[2] + ssum[3];
        const float cnt   = scnt[0] + scnt[1] + scnt[2] + scnt[3];
        const float loss  = total / cnt;
        out[0] = loss;   // loss (shape (1,))
        out[1] = 0.0f;   // recon = jnp.asarray(0)
        out[2] = loss;   // loss again (3rd tuple element)
    }
}

extern "C" void kernel_launch(void* const* d_in, const int* in_sizes, int n_in,
                              void* d_out, int out_size, void* d_ws, size_t ws_size,
                              hipStream_t stream) {
    const float4* logits4 = (const float4*)d_in[0];  // out_seg
    const int4*   seg4    = (const int4*)d_in[1];    // segmentations
    const int*    label   = (const int*)d_in[2];     // label
    float* out     = (float*)d_out;
    float* partial = (float*)d_ws;                   // 1728 floats scratch

    dim3 grid(GRIDX, NROW);
    focal_partial<<<grid, BLOCK, 0, stream>>>(logits4, seg4, label, partial);
    focal_final<<<1, 256, 0, stream>>>(partial, GRIDX * NROW, label, NROW, out);
}